// Round 1
// baseline (204.880 us; speedup 1.0000x reference)
//
#include <hip/hip_runtime.h>

#define C_DIM 28
#define HALF 14
#define HW 65536   // 256*256
#define ITER 2     // pixels per thread: (b0, hw) and (b0+8, hw)
#define THREADS 256
#define GRID 2048  // 2048*256 threads * 2 px = 16*65536 pixels exactly

namespace {

constexpr double K_PI = 3.14159265358979323846;

constexpr double cos_taylor(double u) {
    double u2 = u * u;
    double term = 1.0, sum = 1.0;
    for (int i = 1; i <= 12; ++i) {
        term *= -u2 / (double)((2 * i - 1) * (2 * i));
        sum += term;
    }
    return sum;
}

// cos(pi * t / 56), exact integer range reduction (period 112).
constexpr double cos_pi_over56(int t) {
    t %= 112;
    if (t < 0) t += 112;
    double sign = 1.0;
    if (t > 56) t = 112 - t;
    if (t > 28) { t = 56 - t; sign = -1.0; }
    return sign * cos_taylor(K_PI * (double)t / 56.0);
}

// Symmetry-folded tables.
// D[k][n]    = 2*cos(pi*(2n+1)k/56), n<14.  D[k][27-n] = (-1)^k D[k][n].
// Dinv[n][k] = cos(pi*(2n+1)k/56)*(k==0?0.5:1)/28, n<14.
//              Dinv[27-n][k] = (-1)^k Dinv[n][k].
struct Tables {
    float D[C_DIM][HALF];
    float Dinv[HALF][C_DIM];
};

constexpr Tables make_tables() {
    Tables t{};
    for (int k = 0; k < C_DIM; ++k)
        for (int n = 0; n < HALF; ++n)
            t.D[k][n] = (float)(2.0 * cos_pi_over56((2 * n + 1) * k));
    for (int n = 0; n < HALF; ++n)
        for (int k = 0; k < C_DIM; ++k)
            t.Dinv[n][k] = (float)(cos_pi_over56((2 * n + 1) * k) *
                                   ((k == 0) ? 0.5 : 1.0) / (double)C_DIM);
    return t;
}

constexpr Tables TBL = make_tables();

} // namespace

// Thread t handles pixels (b0, hw) and (b0+8, hw); hw = t & 0xFFFF, b0 = t>>16.
// Weight row (shared by both pixels) loaded once as 7x float4.
// Symmetry fold halves the FMA count: 28 chains of length 14 per matvec.
__global__ __launch_bounds__(THREADS) void spedct_kernel(
    const float* __restrict__ x,
    const float* __restrict__ w,
    float* __restrict__ out) {

    const int t  = blockIdx.x * THREADS + threadIdx.x;  // 0..524287
    const int hw = t & (HW - 1);
    const int b0 = t >> 16;                             // 0..7

    // Weight row: 28 contiguous floats (112 B, 16B-aligned) -> 7x float4, once.
    float wv[C_DIM];
    const float4* wp4 = (const float4*)(w + (size_t)hw * C_DIM);
#pragma unroll
    for (int i = 0; i < 7; ++i) {
        float4 v = wp4[i];
        wv[4 * i + 0] = v.x; wv[4 * i + 1] = v.y;
        wv[4 * i + 2] = v.z; wv[4 * i + 3] = v.w;
    }

    const size_t bstride = (size_t)8 * C_DIM * HW;      // advance b by 8
    const float* xp = x   + (size_t)b0 * C_DIM * HW + hw;
    float*       op = out + (size_t)b0 * C_DIM * HW + hw;

    // Double-buffered channel vector: prefetch pixel 1 while computing pixel 0.
    // Nontemporal: x is read exactly once; keep L2/L3 for the weight.
    float xv[2][C_DIM];
#pragma unroll
    for (int n = 0; n < C_DIM; ++n)
        xv[0][n] = __builtin_nontemporal_load(xp + (size_t)n * HW);

#pragma unroll
    for (int i = 0; i < ITER; ++i) {
        if (i + 1 < ITER) {
            const float* xn = xp + (size_t)(i + 1) * bstride;
#pragma unroll
            for (int n = 0; n < C_DIM; ++n)
                xv[i + 1][n] = __builtin_nontemporal_load(xn + (size_t)n * HW);
        }
        const float* xc = xv[i];

        // Symmetric/antisymmetric fold of the channel vector.
        float s[HALF], u[HALF];
#pragma unroll
        for (int n = 0; n < HALF; ++n) {
            s[n] = xc[n] + xc[27 - n];
            u[n] = xc[n] - xc[27 - n];
        }

        // Xd = D * x via fold: even k uses s, odd k uses u.
        // 28 independent chains of length 14.
        float xd[C_DIM];
#pragma unroll
        for (int k = 0; k < C_DIM; ++k)
            xd[k] = TBL.D[k][0] * ((k & 1) ? u[0] : s[0]);
#pragma unroll
        for (int n = 1; n < HALF; ++n) {
#pragma unroll
            for (int k = 0; k < C_DIM; ++k)
                xd[k] = fmaf(TBL.D[k][n], (k & 1) ? u[n] : s[n], xd[k]);
        }

        // Spectral filter.
#pragma unroll
        for (int k = 0; k < C_DIM; ++k) xd[k] *= wv[k];

        // out = Dinv * xd via fold: e[n] = even-k partial, f[n] = odd-k partial.
        // o[n] = e+f, o[27-n] = e-f.  28 independent chains of length 14.
        float e[HALF], f[HALF];
#pragma unroll
        for (int n = 0; n < HALF; ++n) {
            e[n] = TBL.Dinv[n][0] * xd[0];
            f[n] = TBL.Dinv[n][1] * xd[1];
        }
#pragma unroll
        for (int j = 1; j < HALF; ++j) {
#pragma unroll
            for (int n = 0; n < HALF; ++n) {
                e[n] = fmaf(TBL.Dinv[n][2 * j],     xd[2 * j],     e[n]);
                f[n] = fmaf(TBL.Dinv[n][2 * j + 1], xd[2 * j + 1], f[n]);
            }
        }

        // Nontemporal stores: out is written once, never read.
        float* oo = op + (size_t)i * bstride;
#pragma unroll
        for (int n = 0; n < HALF; ++n) {
            __builtin_nontemporal_store(e[n] + f[n], &oo[(size_t)n * HW]);
            __builtin_nontemporal_store(e[n] - f[n], &oo[(size_t)(27 - n) * HW]);
        }
    }
}

extern "C" void kernel_launch(void* const* d_in, const int* in_sizes, int n_in,
                              void* d_out, int out_size, void* d_ws, size_t ws_size,
                              hipStream_t stream) {
    const float* x = (const float*)d_in[0];   // [16,28,256,256]
    const float* w = (const float*)d_in[1];   // [256,256,28]
    float* out = (float*)d_out;               // [16,28,256,256]

    spedct_kernel<<<dim3(GRID), dim3(THREADS), 0, stream>>>(x, w, out);
}